// Round 6
// baseline (1913.163 us; speedup 1.0000x reference)
//
#include <hip/hip_runtime.h>
#include <hip/hip_bf16.h>
#include <cmath>

// ============================================================================
// RAE forward, round 6: NHWC split-plane bf16x3 MFMA convs.
//   Activations: NHWC, two ushort planes (hi/lo bf16 legs; v == hi+lo).
//   Weights: pre-split into LDS-tile layout aw[(t*C/8+kcg)*O+o][8] hi/lo.
//   Product via 3 MFMAs (AhBh+AhBl+AlBh), fp32 accumulate.
//   DEC = 4 parity sub-convs (same audited tap geometry as rounds 4/5).
//   Epilogue stores o-innermost (full-line writes even with parity stride).
//   dconv4: one thread = 2x2 output parity block, input read once.
// ============================================================================

typedef short  bf16x8 __attribute__((ext_vector_type(8)));
typedef float  f32x4  __attribute__((ext_vector_type(4)));
typedef ushort u16x8  __attribute__((ext_vector_type(8)));
typedef ushort u16x4  __attribute__((ext_vector_type(4)));

__device__ __forceinline__ ushort f2bf(float f) {
    uint u = __float_as_uint(f);
    return (ushort)((u + 0x7fffu + ((u >> 16) & 1u)) >> 16);   // RNE
}
__device__ __forceinline__ float bf2f(ushort h) {
    return __uint_as_float(((uint)h) << 16);                   // exact
}

// ---------------------------------------------------------------------------
// repack + split: wh/wl[((t*(C/8)+kcg)*O+o)*8+j] = hi/lo(W[o][8kcg+j][t])
// ---------------------------------------------------------------------------
__global__ __launch_bounds__(256)
void repack_kernel(const float* __restrict__ W, ushort* __restrict__ wh,
                   ushort* __restrict__ wl, int O, int C)
{
    int i = blockIdx.x * 256 + threadIdx.x;
    if (i >= O * C * 9) return;
    int j = i & 7;
    int rest = i >> 3;
    int o = rest % O;
    int rest2 = rest / O;
    int C8 = C >> 3;
    int kcg = rest2 % C8;
    int t = rest2 / C8;
    float v = W[(o * C + 8 * kcg + j) * 9 + t];
    ushort h = f2bf(v);
    wh[i] = h;
    wl[i] = f2bf(v - bf2f(h));
}

// ---------------------------------------------------------------------------
// conv1: x(256,3,64,64) fp32 -> y NHWC split (256,32,32,128), relu.
// grid (B, 8 o-groups), block 256.
// ---------------------------------------------------------------------------
__global__ __launch_bounds__(256)
void conv1_kernel(const float* __restrict__ x, const float* __restrict__ W,
                  const float* __restrict__ bias, ushort* __restrict__ yh,
                  ushort* __restrict__ yl)
{
    __shared__ float xs[3 * 64 * 64];
    __shared__ float ws[16 * 27];
    __shared__ float bs[16];
    const int n = blockIdx.x, og = blockIdx.y;
    const int tid = threadIdx.x;
    const float* xp = x + (size_t)n * 3 * 64 * 64;
    for (int i = tid; i < 3 * 64 * 64 / 4; i += 256)
        ((float4*)xs)[i] = ((const float4*)xp)[i];
    for (int i = tid; i < 16 * 27; i += 256)
        ws[i] = W[(og * 16 + i / 27) * 27 + i % 27];
    if (tid < 16) bs[tid] = bias[og * 16 + tid];
    __syncthreads();

    for (int p = 0; p < 4; p++) {
        int pos = tid + 256 * p;              // site u*32+v
        int u = pos >> 5, v = pos & 31;
        float xv[27];
#pragma unroll
        for (int c = 0; c < 3; c++)
#pragma unroll
            for (int kh = 0; kh < 3; kh++)
#pragma unroll
                for (int kw = 0; kw < 3; kw++) {
                    int iu = 2 * u - 1 + kh, iv = 2 * v - 1 + kw;
                    bool ok = (iu >= 0) & (iu < 64) & (iv >= 0) & (iv < 64);
                    xv[c * 9 + kh * 3 + kw] = ok ? xs[(c << 12) + (iu << 6) + iv] : 0.f;
                }
        u16x8 hv0, hv1, lv0, lv1;
#pragma unroll
        for (int oi = 0; oi < 16; oi++) {
            float acc = bs[oi];
#pragma unroll
            for (int t = 0; t < 27; t++) acc = fmaf(xv[t], ws[oi * 27 + t], acc);
            acc = fmaxf(acc, 0.f);
            ushort h = f2bf(acc);
            ushort l = f2bf(acc - bf2f(h));
            if (oi < 8) { hv0[oi] = h; lv0[oi] = l; }
            else        { hv1[oi - 8] = h; lv1[oi - 8] = l; }
        }
        const size_t base = ((size_t)n * 1024 + pos) * 128 + og * 16;
        *(u16x8*)&yh[base]     = hv0;
        *(u16x8*)&yh[base + 8] = hv1;
        *(u16x8*)&yl[base]     = lv0;
        *(u16x8*)&yl[base + 8] = lv1;
    }
}

// ---------------------------------------------------------------------------
// MFMA implicit-GEMM conv (bf16x3, NHWC split planes). BM in {64,128}, BN=128.
// 4 waves 2x2; wave tile (BM/2)x64 = MFR x 4 frags of 16x16x32.
// Tap geometry identical to validated rounds 4/5.
// A LDS [kc][BM][8] (conflict-free), B LDS [128][40] padded rows.
// ---------------------------------------------------------------------------
template<bool DEC, int BM>
__global__ __launch_bounds__(256)
void conv_mfma(const ushort* __restrict__ xh, const ushort* __restrict__ xl,
               const ushort* __restrict__ awh, const ushort* __restrict__ awl,
               const float* __restrict__ bias,
               ushort* __restrict__ yh, ushort* __restrict__ yl,
               float* __restrict__ fout,
               int C, int Hi, int Wi, int O, int Ho, int Wo,
               int lgGW, int lgGHW, int act)
{
    constexpr int MFR = BM / 32;
    constexpr int ACH = BM / 64;
    __shared__ __align__(16) ushort Ash[4][BM][8];
    __shared__ __align__(16) ushort Asl[4][BM][8];
    __shared__ __align__(16) ushort Bsh[128][40];
    __shared__ __align__(16) ushort Bsl[128][40];

    const int tid = threadIdx.x;
    const int lane = tid & 63, wv = tid >> 6;
    const int wr = wv >> 1, wc = wv & 1;
    const int lr = lane & 15, lq = lane >> 4;

    const int o0 = blockIdx.y * BM;
    const int s0 = blockIdx.x * 128;

    int pi = 0, pj = 0, ntv = 0, nth = 0;
    if (DEC) {
        pi = blockIdx.z >> 1; pj = blockIdx.z & 1;
        ntv = (pi == 1) ? 1 : 2;
        nth = (pj == 1) ? 1 : 2;
    }
    const int gwm = (1 << lgGW) - 1, ghwm = (1 << lgGHW) - 1;
    const int C8 = C >> 3;

    // B staging: kc fast across lanes (coalesced 64B/site), 2 sites/thread
    const int kcB = tid & 3;
    const int spB = tid >> 2;          // 0..63
    int nS[2], uS[2], vS[2];
#pragma unroll
    for (int q = 0; q < 2; q++) {
        int s = s0 + spB + 64 * q;
        nS[q] = s >> lgGHW;
        int r = s & ghwm;
        uS[q] = r >> lgGW;
        vS[q] = r & gwm;
    }
    // A staging: o fast across lanes (coalesced 1KB), kc per wave
    const int kcA = tid >> 6;
    const int oA = tid & 63;

    f32x4 acc[MFR][4] = {};

    const int ntaps = DEC ? ntv * nth : 9;
    for (int t = 0; t < ntaps; t++) {
        int tapidx;
        int sbase[2]; bool valid[2];
        if (!DEC) {
            int kh = t / 3, kw = t % 3;
            tapidx = t;
#pragma unroll
            for (int q = 0; q < 2; q++) {
                int iu = 2 * uS[q] - 1 + kh, iv = 2 * vS[q] - 1 + kw;
                valid[q] = (iu >= 0) & (iu < Hi) & (iv >= 0) & (iv < Wi);
                sbase[q] = ((nS[q] * Hi + iu) * Wi + iv) * C;
            }
        } else {
            int itv = t / nth, ith = t - (t / nth) * nth;
            int kh = (pi == 1) ? 1 : 2 - 2 * itv;   // da = itv
            int kw = (pj == 1) ? 1 : 2 - 2 * ith;   // db = ith
            tapidx = kh * 3 + kw;
#pragma unroll
            for (int q = 0; q < 2; q++) {
                int a = uS[q] - itv, b2 = vS[q] - ith;
                valid[q] = (a >= 0) & (b2 >= 0);
                sbase[q] = ((nS[q] * Hi + a) * Wi + b2) * C;
            }
        }
        const size_t wtap = (size_t)tapidx * C8 * O * 8;
        for (int c0 = 0; c0 < C; c0 += 32) {
            __syncthreads();   // WAR: previous step's frag reads done
            {   // stage A: pure 16B copies
                const size_t koff = wtap + (size_t)((c0 >> 3) + kcA) * O * 8;
#pragma unroll
                for (int q = 0; q < ACH; q++) {
                    const int o = oA + 64 * q;
                    const size_t aoff = koff + (size_t)(o0 + o) * 8;
                    *(u16x8*)&Ash[kcA][o][0] = *(const u16x8*)&awh[aoff];
                    *(u16x8*)&Asl[kcA][o][0] = *(const u16x8*)&awl[aoff];
                }
            }
            {   // stage B: vector loads, no unpack
#pragma unroll
                for (int q = 0; q < 2; q++) {
                    const int sp = spB + 64 * q;
                    u16x8 vh, vl2;
                    if (valid[q]) {
                        const int goff = sbase[q] + c0 + 8 * kcB;
                        vh  = *(const u16x8*)&xh[goff];
                        vl2 = *(const u16x8*)&xl[goff];
                    } else {
#pragma unroll
                        for (int j = 0; j < 8; j++) { vh[j] = 0; vl2[j] = 0; }
                    }
                    *(u16x8*)&Bsh[sp][8 * kcB] = vh;
                    *(u16x8*)&Bsl[sp][8 * kcB] = vl2;
                }
            }
            __syncthreads();
            bf16x8 bh[4], bl[4];
#pragma unroll
            for (int nf = 0; nf < 4; nf++) {
                const int nn = wc * 64 + nf * 16 + lr;
                bh[nf] = *(const bf16x8*)&Bsh[nn][8 * lq];
                bl[nf] = *(const bf16x8*)&Bsl[nn][8 * lq];
            }
#pragma unroll
            for (int mf = 0; mf < MFR; mf++) {
                const int m = wr * (BM / 2) + mf * 16 + lr;
                bf16x8 ah = *(const bf16x8*)&Ash[lq][m][0];
                bf16x8 al = *(const bf16x8*)&Asl[lq][m][0];
#pragma unroll
                for (int nf = 0; nf < 4; nf++) {
                    acc[mf][nf] = __builtin_amdgcn_mfma_f32_16x16x32_bf16(ah, bh[nf], acc[mf][nf], 0, 0, 0);
                    acc[mf][nf] = __builtin_amdgcn_mfma_f32_16x16x32_bf16(ah, bl[nf], acc[mf][nf], 0, 0, 0);
                    acc[mf][nf] = __builtin_amdgcn_mfma_f32_16x16x32_bf16(al, bh[nf], acc[mf][nf], 0, 0, 0);
                }
            }
        }
    }

    const int HoWo = Ho * Wo;
#pragma unroll
    for (int mf = 0; mf < MFR; mf++) {
        const int obase = o0 + wr * (BM / 2) + mf * 16 + 4 * lq;
        const float4 b4 = *(const float4*)&bias[obase];
#pragma unroll
        for (int nf = 0; nf < 4; nf++) {
            const int s = s0 + wc * 64 + nf * 16 + lr;
            const int n = s >> lgGHW;
            const int r = s & ghwm;
            const int u = r >> lgGW, v = r & gwm;
            const int U = DEC ? 2 * u + pi : u;
            const int V = DEC ? 2 * v + pj : v;
            const size_t yidx = ((size_t)(n * Ho + U) * Wo + V) * O + obase;
            float vals[4];
            vals[0] = acc[mf][nf][0] + b4.x;
            vals[1] = acc[mf][nf][1] + b4.y;
            vals[2] = acc[mf][nf][2] + b4.z;
            vals[3] = acc[mf][nf][3] + b4.w;
            u16x4 hv, lv;
#pragma unroll
            for (int i = 0; i < 4; i++) {
                float val = vals[i];
                val = (act == 0) ? fmaxf(val, 0.f) : 1.f / (1.f + expf(-val));
                vals[i] = val;
                ushort h = f2bf(val);
                hv[i] = h;
                lv[i] = f2bf(val - bf2f(h));
            }
            *(u16x4*)&yh[yidx] = hv;
            *(u16x4*)&yl[yidx] = lv;
            if (fout) {
#pragma unroll
                for (int i = 0; i < 4; i++)
                    fout[(size_t)n * O * HoWo + (size_t)(obase + i) * HoWo + U * Wo + V] = vals[i];
            }
        }
    }
}

// ---------------------------------------------------------------------------
// dconv4: x NHWC split (256,32,32,128) -> y(256,3,64,64) fp32, sigmoid.
// One thread = 2x2 output parity block at input site (u,v); input read once.
// grid (4, 256), block 256.
// ---------------------------------------------------------------------------
__device__ __forceinline__ void load8f(float* d, const ushort* hp, const ushort* lp, bool ok)
{
    if (ok) {
        u16x8 h = *(const u16x8*)hp, l = *(const u16x8*)lp;
#pragma unroll
        for (int j = 0; j < 8; j++) d[j] = bf2f(h[j]) + bf2f(l[j]);
    } else {
#pragma unroll
        for (int j = 0; j < 8; j++) d[j] = 0.f;
    }
}

__global__ __launch_bounds__(256)
void dconv4_kernel(const ushort* __restrict__ xh, const ushort* __restrict__ xl,
                   const float* __restrict__ W, const float* __restrict__ bias,
                   float* __restrict__ y)
{
    __shared__ float ws[3456];   // W[o][c][kh*3+kw], o stride 1152
    const int tid = threadIdx.x;
    for (int i = tid; i < 3456; i += 256) ws[i] = W[i];
    __syncthreads();
    const int n = blockIdx.y;
    const int pos = blockIdx.x * 256 + tid;   // u*32+v
    const int u = pos >> 5, v = pos & 31;

    float acc[2][2][3];
#pragma unroll
    for (int pi_ = 0; pi_ < 2; pi_++)
#pragma unroll
        for (int pj_ = 0; pj_ < 2; pj_++)
#pragma unroll
            for (int o = 0; o < 3; o++) acc[pi_][pj_][o] = bias[o];

    const size_t b00 = ((size_t)n * 1024 + pos) * 128;
    const size_t b10 = b00 - 32 * 128;   // (u-1, v)
    const size_t b01 = b00 - 128;        // (u, v-1)
    const size_t b11 = b00 - 33 * 128;   // (u-1, v-1)
    const bool vu = (u > 0), vv = (v > 0);

    for (int kc = 0; kc < 16; kc++) {
        const int co = kc * 8;
        float x00[8], x10[8], x01[8], x11[8];
        load8f(x00, &xh[b00 + co], &xl[b00 + co], true);
        load8f(x10, &xh[b10 + co], &xl[b10 + co], vu);
        load8f(x01, &xh[b01 + co], &xl[b01 + co], vv);
        load8f(x11, &xh[b11 + co], &xl[b11 + co], vu && vv);
#pragma unroll
        for (int j = 0; j < 8; j++) {
            const int c9 = (co + j) * 9;
#pragma unroll
            for (int o = 0; o < 3; o++) {
                const float* w = &ws[o * 1152 + c9];
                // (pi,pj)=(0,0): taps (kh,kw)=(2,2)x00 (2,0)x01 (0,2)x10 (0,0)x11
                acc[0][0][o] = fmaf(x00[j], w[8], acc[0][0][o]);
                acc[0][0][o] = fmaf(x01[j], w[6], acc[0][0][o]);
                acc[0][0][o] = fmaf(x10[j], w[2], acc[0][0][o]);
                acc[0][0][o] = fmaf(x11[j], w[0], acc[0][0][o]);
                // (0,1): (2,1)x00 (0,1)x10
                acc[0][1][o] = fmaf(x00[j], w[7], acc[0][1][o]);
                acc[0][1][o] = fmaf(x10[j], w[1], acc[0][1][o]);
                // (1,0): (1,2)x00 (1,0)x01
                acc[1][0][o] = fmaf(x00[j], w[5], acc[1][0][o]);
                acc[1][0][o] = fmaf(x01[j], w[3], acc[1][0][o]);
                // (1,1): (1,1)x00
                acc[1][1][o] = fmaf(x00[j], w[4], acc[1][1][o]);
            }
        }
    }
#pragma unroll
    for (int o = 0; o < 3; o++)
#pragma unroll
        for (int pi_ = 0; pi_ < 2; pi_++) {
            float2 val;
            val.x = 1.f / (1.f + expf(-acc[pi_][0][o]));
            val.y = 1.f / (1.f + expf(-acc[pi_][1][o]));
            *(float2*)&y[(size_t)n * 12288 + o * 4096 + (2 * u + pi_) * 64 + 2 * v] = val;
        }
}

// ---------------------------------------------------------------------------
// rownorm[r] = ||row_r||^2 over 4096 cols. grid 256, block 64.
// ---------------------------------------------------------------------------
__global__ __launch_bounds__(64)
void pnorm_kernel(const float* __restrict__ rows, float* __restrict__ norms)
{
    const int r = blockIdx.x, lane = threadIdx.x;
    const float* pr = rows + (size_t)r * 4096;
    float s = 0.f;
    for (int d = lane; d < 4096; d += 64) s = fmaf(pr[d], pr[d], s);
#pragma unroll
    for (int off = 32; off; off >>= 1) s += __shfl_xor(s, off);
    if (lane == 0) norms[r] = s;
}

// ---------------------------------------------------------------------------
// Split-K partial dots: dotpart[ks][b][gp]. grid (64,8), block 256.
// ---------------------------------------------------------------------------
__global__ __launch_bounds__(256)
void dists_part_kernel(const float* __restrict__ latent, const float* __restrict__ protos,
                       float* __restrict__ dotpart)
{
    __shared__ float zl[4][512];
    const int b0 = blockIdx.x * 4, ks = blockIdx.y, tid = threadIdx.x;
    for (int i = tid; i < 512; i += 256) {
        int bb = i >> 7, off = i & 127;
        ((float4*)&zl[bb][0])[off] =
            ((const float4*)(latent + (size_t)(b0 + bb) * 4096 + ks * 512))[off];
    }
    __syncthreads();
    const int w = tid >> 6, lane = tid & 63;
    for (int i = 0; i < 64; i++) {
        const int gp = w * 64 + i;
        const float* pr = protos + (size_t)gp * 4096 + ks * 512;
        float dot[4] = {0.f, 0.f, 0.f, 0.f};
#pragma unroll
        for (int d8 = 0; d8 < 8; d8++) {
            const int d = lane + 64 * d8;
            const float pv = pr[d];
#pragma unroll
            for (int bb = 0; bb < 4; bb++) dot[bb] = fmaf(zl[bb][d], pv, dot[bb]);
        }
#pragma unroll
        for (int bb = 0; bb < 4; bb++)
#pragma unroll
            for (int off = 32; off; off >>= 1) dot[bb] += __shfl_xor(dot[bb], off);
        if (lane == 0) {
#pragma unroll
            for (int bb = 0; bb < 4; bb++)
                dotpart[(size_t)ks * 65536 + (size_t)(b0 + bb) * 256 + gp] = dot[bb];
        }
    }
}

__global__ __launch_bounds__(256)
void dists_final_kernel(const float* __restrict__ dotpart, const float* __restrict__ znorm,
                        const float* __restrict__ pnorm, float* __restrict__ dists)
{
    const int i = blockIdx.x * 256 + threadIdx.x;
    const int b = i >> 8, gp = i & 255;
    float s = 0.f;
#pragma unroll
    for (int ks = 0; ks < 8; ks++) s += dotpart[(size_t)ks * 65536 + i];
    dists[i] = znorm[b] + pnorm[gp] - 2.f * s;
}

// ---------------------------------------------------------------------------
// softmin + mix. grid (64 bgroups, 16 dchunks), block 256.
// Also writes mixed as NHWC split planes for dconv1.
// ---------------------------------------------------------------------------
__global__ __launch_bounds__(256)
void softmix_kernel(const float* __restrict__ dists, const float* __restrict__ protos,
                    const float* __restrict__ pw, float* __restrict__ mixed,
                    ushort* __restrict__ mh, ushort* __restrict__ ml)
{
    __shared__ float sml[4][256];
    const int b0 = blockIdx.x * 4, d0 = blockIdx.y * 256, tid = threadIdx.x;
    const int w = tid >> 6, lane = tid & 63;
#pragma unroll
    for (int g = 0; g < 4; g++) {
        float dv = -dists[(size_t)(b0 + w) * 256 + g * 64 + lane];
        float m = dv;
#pragma unroll
        for (int off = 32; off; off >>= 1) m = fmaxf(m, __shfl_xor(m, off));
        float e = expf(dv - m);
        float s = e;
#pragma unroll
        for (int off = 32; off; off >>= 1) s += __shfl_xor(s, off);
        sml[w][g * 64 + lane] = e / s;
    }
    __syncthreads();
    const int d = d0 + tid;
    const int oo = d >> 4, sp = d & 15;   // NCHW d -> (o, site)
    float accg[4][4];
#pragma unroll
    for (int bb = 0; bb < 4; bb++)
#pragma unroll
        for (int g = 0; g < 4; g++) accg[bb][g] = 0.f;
#pragma unroll
    for (int g = 0; g < 4; g++)
        for (int p = 0; p < 64; p++) {
            float pv = protos[(size_t)(g * 64 + p) * 4096 + d];
#pragma unroll
            for (int bb = 0; bb < 4; bb++)
                accg[bb][g] = fmaf(sml[bb][g * 64 + p], pv, accg[bb][g]);
        }
    float pwv[4];
#pragma unroll
    for (int g = 0; g < 4; g++) pwv[g] = pw[g * 4096 + d];
#pragma unroll
    for (int bb = 0; bb < 4; bb++) {
        float m = 0.f;
#pragma unroll
        for (int g = 0; g < 4; g++) m = fmaf(pwv[g], accg[bb][g], m);
        m *= 0.25f;
        mixed[(size_t)(b0 + bb) * 4096 + d] = m;
        const size_t pidx = ((size_t)(b0 + bb) * 16 + sp) * 256 + oo;
        ushort h = f2bf(m);
        mh[pidx] = h;
        ml[pidx] = f2bf(m - bf2f(h));
    }
}

// ============================================================================
extern "C" void kernel_launch(void* const* d_in, const int* in_sizes, int n_in,
                              void* d_out, int out_size, void* d_ws, size_t ws_size,
                              hipStream_t stream)
{
    const float* x    = (const float*)d_in[0];
    const float* We1  = (const float*)d_in[1];  const float* be1 = (const float*)d_in[2];
    const float* We2  = (const float*)d_in[3];  const float* be2 = (const float*)d_in[4];
    const float* We3  = (const float*)d_in[5];  const float* be3 = (const float*)d_in[6];
    const float* We4  = (const float*)d_in[7];  const float* be4 = (const float*)d_in[8];
    const float* Wd1  = (const float*)d_in[9];  const float* bd1 = (const float*)d_in[10];
    const float* Wd2  = (const float*)d_in[11]; const float* bd2 = (const float*)d_in[12];
    const float* Wd3  = (const float*)d_in[13]; const float* bd3 = (const float*)d_in[14];
    const float* Wd4  = (const float*)d_in[15]; const float* bd4 = (const float*)d_in[16];
    const float* protos = (const float*)d_in[17];
    const float* pw   = (const float*)d_in[18];

    float* out = (float*)d_out;
    float* recon_img   = out;               // (256,3,64,64)
    float* recon_proto = out + 3145728;     // (256,3,64,64)
    float* dists       = out + 6291456;     // (256,4,64)
    float* latent      = out + 6356992;     // (256,256,4,4) fp32 NCHW
    float* out_protos  = out + 7405568;     // (4,64,4096)
    float* mixed       = out + 8454144;     // (256,4096)

    ushort* wsu  = (ushort*)d_ws;
    ushort* bufAh = wsu;                    // 33,554,432 each plane
    ushort* bufAl = bufAh + 33554432;
    ushort* bufBh = bufAl + 33554432;       //  8,388,608
    ushort* bufBl = bufBh + 8388608;
    ushort* bufCh = bufBl + 8388608;        //  2,097,152
    ushort* bufCl = bufCh + 2097152;
    ushort* bufLh = bufCl + 2097152;        //  1,048,576
    ushort* bufLl = bufLh + 1048576;
    ushort* bufMh = bufLl + 1048576;        //  1,048,576
    ushort* bufMl = bufMh + 1048576;
    ushort* wc2h = bufMl + 1048576;         //    147,456 each
    ushort* wc2l = wc2h + 147456;
    ushort* wc3h = wc2l + 147456;
    ushort* wc3l = wc3h + 147456;
    ushort* wc4h = wc3l + 147456;           //    294,912 each
    ushort* wc4l = wc4h + 294912;
    ushort* wd1h = wc4l + 294912;           //    294,912 each
    ushort* wd1l = wd1h + 294912;
    ushort* wd2h = wd1l + 294912;           //    147,456 each
    ushort* wd2l = wd2h + 147456;
    ushort* wd3h = wd2l + 147456;
    ushort* wd3l = wd3h + 147456;
    float* pnorm = (float*)(wd3l + 147456); //        256
    float* znorm = pnorm + 256;             //        256
    float* dotpart = znorm + 256;           //    524,288

    // weight repack+split (d_ws re-poisoned every call -> redo every call)
    repack_kernel<<<576, 256, 0, stream>>>(We2, wc2h, wc2l, 128, 128);
    repack_kernel<<<576, 256, 0, stream>>>(We3, wc3h, wc3l, 128, 128);
    repack_kernel<<<1152, 256, 0, stream>>>(We4, wc4h, wc4l, 256, 128);
    repack_kernel<<<1152, 256, 0, stream>>>(Wd1, wd1h, wd1l, 128, 256);
    repack_kernel<<<576, 256, 0, stream>>>(Wd2, wd2h, wd2l, 128, 128);
    repack_kernel<<<576, 256, 0, stream>>>(Wd3, wd3h, wd3l, 128, 128);
    pnorm_kernel<<<256, 64, 0, stream>>>(protos, pnorm);

    // encoder
    conv1_kernel<<<dim3(256, 8), 256, 0, stream>>>(x, We1, be1, bufAh, bufAl);
    conv_mfma<false, 128><<<dim3(512, 1), 256, 0, stream>>>(
        bufAh, bufAl, wc2h, wc2l, be2, bufBh, bufBl, nullptr,
        128, 32, 32, 128, 16, 16, 4, 8, 0);
    conv_mfma<false, 64><<<dim3(128, 2), 256, 0, stream>>>(
        bufBh, bufBl, wc3h, wc3l, be3, bufCh, bufCl, nullptr,
        128, 16, 16, 128, 8, 8, 3, 6, 0);
    conv_mfma<false, 64><<<dim3(32, 4), 256, 0, stream>>>(
        bufCh, bufCl, wc4h, wc4l, be4, bufLh, bufLl, latent,
        128, 8, 8, 256, 4, 4, 2, 4, 1);

    // prototype block (fp32)
    pnorm_kernel<<<256, 64, 0, stream>>>(latent, znorm);
    dists_part_kernel<<<dim3(64, 8), 256, 0, stream>>>(latent, protos, dotpart);
    dists_final_kernel<<<256, 256, 0, stream>>>(dotpart, znorm, pnorm, dists);
    softmix_kernel<<<dim3(64, 16), 256, 0, stream>>>(dists, protos, pw, mixed,
                                                     bufMh, bufMl);
    hipMemcpyAsync(out_protos, protos, 1048576 * sizeof(float),
                   hipMemcpyDeviceToDevice, stream);

    // two decoders (share scratch; stream order serializes)
    for (int pass = 0; pass < 2; pass++) {
        const ushort* sh = (pass == 0) ? bufMh : bufLh;
        const ushort* sl = (pass == 0) ? bufMl : bufLl;
        float* dst = (pass == 0) ? recon_proto : recon_img;
        conv_mfma<true, 64><<<dim3(32, 2, 4), 256, 0, stream>>>(
            sh, sl, wd1h, wd1l, bd1, bufCh, bufCl, nullptr,
            256, 4, 4, 128, 8, 8, 2, 4, 0);
        conv_mfma<true, 128><<<dim3(128, 1, 4), 256, 0, stream>>>(
            bufCh, bufCl, wd2h, wd2l, bd2, bufBh, bufBl, nullptr,
            128, 8, 8, 128, 16, 16, 3, 6, 0);
        conv_mfma<true, 128><<<dim3(512, 1, 4), 256, 0, stream>>>(
            bufBh, bufBl, wd3h, wd3l, bd3, bufAh, bufAl, nullptr,
            128, 16, 16, 128, 32, 32, 4, 8, 0);
        dconv4_kernel<<<dim3(4, 256), 256, 0, stream>>>(bufAh, bufAl, Wd4, bd4, dst);
    }
}